// Round 1
// baseline (1047.349 us; speedup 1.0000x reference)
//
#include <hip/hip_runtime.h>
#include <math.h>

#define B 8
#define S 512
#define D 512
#define H 8
#define DH 64
#define VOCAB (2 * (S - 1) + 1)   // 1023

// ---------------------------------------------------------------------------
// Recover the 1023-row sinusoidal table from pos_emb:
// pos_emb[q,k,:] = pe[k - q + 511].  Row q=511 gives pe[0..511], row q=0
// gives pe[511..1022].
// ---------------------------------------------------------------------------
__global__ void build_pe(const float* __restrict__ pos_emb, float* __restrict__ pe) {
    int idx = blockIdx.x * blockDim.x + threadIdx.x; // over VOCAB*D
    if (idx >= VOCAB * D) return;
    int d = idx / D, c = idx % D;
    int q = (d < S) ? (S - 1) : 0;
    int k = (d < S) ? d : (d - (S - 1));
    pe[idx] = pos_emb[(q * S + k) * D + c];
}

// ---------------------------------------------------------------------------
// C[M,N] = A[M,K] @ W[N,K]^T + bias[N] (+ residual[M,N] if given)
// 64x64 tile, BK=32, 256 threads, 4x4 outputs/thread. f32 baseline.
// ---------------------------------------------------------------------------
__global__ __launch_bounds__(256) void gemm_bt(
    const float* __restrict__ A, const float* __restrict__ W,
    const float* __restrict__ bias, const float* __restrict__ resid,
    float* __restrict__ C, int M, int N, int K)
{
    const int BM = 64, BN = 64, BK = 32;
    __shared__ float As[BM][BK + 1];
    __shared__ float Ws[BN][BK + 1];
    int tid = threadIdx.x;
    int m0 = blockIdx.y * BM, n0 = blockIdx.x * BN;
    int tx = tid % 16, ty = tid / 16;
    float acc[4][4] = {};

    for (int k0 = 0; k0 < K; k0 += BK) {
        #pragma unroll
        for (int l = 0; l < (BM * BK) / 256; ++l) {
            int e = tid + l * 256;
            int r = e / BK, c = e % BK;
            int gm = m0 + r;
            As[r][c] = (gm < M) ? A[gm * K + k0 + c] : 0.f;
        }
        #pragma unroll
        for (int l = 0; l < (BN * BK) / 256; ++l) {
            int e = tid + l * 256;
            int r = e / BK, c = e % BK;
            Ws[r][c] = W[(n0 + r) * K + k0 + c];
        }
        __syncthreads();
        #pragma unroll
        for (int kk = 0; kk < BK; ++kk) {
            float a[4], wv[4];
            #pragma unroll
            for (int i = 0; i < 4; ++i) a[i] = As[4 * ty + i][kk];
            #pragma unroll
            for (int j = 0; j < 4; ++j) wv[j] = Ws[4 * tx + j][kk];
            #pragma unroll
            for (int i = 0; i < 4; ++i)
                #pragma unroll
                for (int j = 0; j < 4; ++j)
                    acc[i][j] += a[i] * wv[j];
        }
        __syncthreads();
    }
    #pragma unroll
    for (int i = 0; i < 4; ++i) {
        int m = m0 + 4 * ty + i;
        if (m >= M) continue;
        #pragma unroll
        for (int j = 0; j < 4; ++j) {
            int n = n0 + 4 * tx + j;
            float v = acc[i][j] + bias[n];
            if (resid) v += resid[m * N + n];
            C[m * N + n] = v;
        }
    }
}

// ---------------------------------------------------------------------------
// Fused relative attention: one block = (b,h) x 16 q-rows.
// scores[q][k] = ( (qh+u)·kh[k] + (qh+v)·Rproj[k-q+511] ) / 8
// softmax over k, then PV.  All f32.
// ---------------------------------------------------------------------------
__global__ __launch_bounds__(256) void attn_kernel(
    const float* __restrict__ qh, const float* __restrict__ kh,
    const float* __restrict__ vh, const float* __restrict__ rproj,
    const float* __restrict__ u_bias, const float* __restrict__ v_bias,
    float* __restrict__ attn_out)
{
    const int QB = 16, KB = 64;
    int bh = blockIdx.x;
    int b = bh / H, h = bh % H;
    int q0 = blockIdx.y * QB;
    int tid = threadIdx.x;
    int w = tid / 64, lane = tid % 64;

    __shared__ float qu_s[QB][DH];
    __shared__ float qv_s[QB][DH];
    __shared__ float k_s[KB][DH + 1];                // reused for V in PV phase
    __shared__ float r_s[QB + KB - 1][DH + 1];       // 79 rows of Rproj band
    __shared__ float sc[QB][S + 4];

    // stage q rows (+u / +v bias)
    #pragma unroll
    for (int l = 0; l < (QB * DH) / 256; ++l) {
        int e = tid + l * 256;
        int r = e / DH, c = e % DH;
        float qv_ = qh[((b * S + q0 + r) * H + h) * DH + c];
        qu_s[r][c] = qv_ + u_bias[h * DH + c];
        qv_s[r][c] = qv_ + v_bias[h * DH + c];
    }
    __syncthreads();

    const float scale = 0.125f; // 1/sqrt(DH)

    // ---- Phase A: scores ----
    for (int kt = 0; kt < S / KB; ++kt) {
        int k0 = kt * KB;
        #pragma unroll
        for (int l = 0; l < (KB * DH) / 256; ++l) {
            int e = tid + l * 256;
            int r = e / DH, c = e % DH;
            k_s[r][c] = kh[((b * S + k0 + r) * H + h) * DH + c];
        }
        int base = k0 - q0 - (QB - 1) + (S - 1);     // >= 0, band fits [0,1022]
        #pragma unroll
        for (int l = 0; l < ((QB + KB - 1) * DH + 255) / 256; ++l) {
            int e = tid + l * 256;
            if (e < (QB + KB - 1) * DH) {
                int r = e / DH, c = e % DH;
                r_s[r][c] = rproj[(base + r) * D + h * DH + c];
            }
        }
        __syncthreads();
        #pragma unroll
        for (int l = 0; l < 4; ++l) {
            int q = l * 4 + w;
            int k = lane;
            const float* qu = qu_s[q];
            const float* qv = qv_s[q];
            const float* kp = k_s[k];
            const float* rp = r_s[k - q + (QB - 1)];
            float s = 0.f;
            #pragma unroll
            for (int d = 0; d < DH; ++d)
                s += qu[d] * kp[d] + qv[d] * rp[d];
            sc[q][k0 + k] = s * scale;
        }
        __syncthreads();
    }

    // ---- Phase B: softmax per row ----
    #pragma unroll
    for (int rr = 0; rr < 4; ++rr) {
        int q = rr * 4 + w;
        float vals[8];
        float m = -1e30f;
        #pragma unroll
        for (int j = 0; j < 8; ++j) {
            vals[j] = sc[q][lane + j * 64];
            m = fmaxf(m, vals[j]);
        }
        #pragma unroll
        for (int off = 32; off; off >>= 1) m = fmaxf(m, __shfl_xor(m, off, 64));
        float sum = 0.f;
        #pragma unroll
        for (int j = 0; j < 8; ++j) { vals[j] = __expf(vals[j] - m); sum += vals[j]; }
        #pragma unroll
        for (int off = 32; off; off >>= 1) sum += __shfl_xor(sum, off, 64);
        float inv = 1.f / sum;
        #pragma unroll
        for (int j = 0; j < 8; ++j) sc[q][lane + j * 64] = vals[j] * inv;
    }
    __syncthreads();

    // ---- Phase C: PV ----
    float acc[4] = {0.f, 0.f, 0.f, 0.f};
    for (int kt = 0; kt < S / KB; ++kt) {
        int k0 = kt * KB;
        #pragma unroll
        for (int l = 0; l < (KB * DH) / 256; ++l) {
            int e = tid + l * 256;
            int r = e / DH, c = e % DH;
            k_s[r][c] = vh[((b * S + k0 + r) * H + h) * DH + c];
        }
        __syncthreads();
        #pragma unroll 8
        for (int k = 0; k < KB; ++k) {
            float vv = k_s[k][lane];
            #pragma unroll
            for (int l = 0; l < 4; ++l)
                acc[l] += sc[l * 4 + w][k0 + k] * vv;
        }
        __syncthreads();
    }
    #pragma unroll
    for (int l = 0; l < 4; ++l) {
        int q = l * 4 + w;
        attn_out[((b * S + q0 + q) * H + h) * DH + lane] = acc[l];
    }
}

// ---------------------------------------------------------------------------
// In-place LayerNorm over last dim (D=512). One wave per row.
// ---------------------------------------------------------------------------
__global__ __launch_bounds__(256) void ln_kernel(
    float* __restrict__ out, const float* __restrict__ g, const float* __restrict__ bta)
{
    int row = blockIdx.x * 4 + threadIdx.x / 64;
    int lane = threadIdx.x % 64;
    float vals[8];
    float sum = 0.f;
    #pragma unroll
    for (int j = 0; j < 8; ++j) {
        vals[j] = out[row * D + lane + j * 64];
        sum += vals[j];
    }
    #pragma unroll
    for (int off = 32; off; off >>= 1) sum += __shfl_xor(sum, off, 64);
    float mu = sum / (float)D;
    float sq = 0.f;
    #pragma unroll
    for (int j = 0; j < 8; ++j) { float dv = vals[j] - mu; sq += dv * dv; }
    #pragma unroll
    for (int off = 32; off; off >>= 1) sq += __shfl_xor(sq, off, 64);
    float rstd = rsqrtf(sq / (float)D + 1e-5f);
    #pragma unroll
    for (int j = 0; j < 8; ++j) {
        int c = lane + j * 64;
        out[row * D + c] = (vals[j] - mu) * rstd * g[c] + bta[c];
    }
}

// ---------------------------------------------------------------------------
extern "C" void kernel_launch(void* const* d_in, const int* in_sizes, int n_in,
                              void* d_out, int out_size, void* d_ws, size_t ws_size,
                              hipStream_t stream) {
    const float* q       = (const float*)d_in[0];
    const float* k       = (const float*)d_in[1];
    const float* v       = (const float*)d_in[2];
    const float* pos_emb = (const float*)d_in[3];
    const float* Wq = (const float*)d_in[4];  const float* bq = (const float*)d_in[5];
    const float* Wk = (const float*)d_in[6];  const float* bk = (const float*)d_in[7];
    const float* Wv = (const float*)d_in[8];  const float* bv = (const float*)d_in[9];
    const float* Wr = (const float*)d_in[10]; const float* br = (const float*)d_in[11];
    const float* Wo = (const float*)d_in[12]; const float* bo = (const float*)d_in[13];
    const float* u_bias = (const float*)d_in[14];
    const float* v_bias = (const float*)d_in[15];
    const float* ln_g = (const float*)d_in[16];
    const float* ln_b = (const float*)d_in[17];

    float* out = (float*)d_out;
    float* ws  = (float*)d_ws;

    float* pe    = ws;                     // VOCAB*D
    float* rproj = pe + VOCAB * D;         // VOCAB*D
    float* qh    = rproj + VOCAB * D;      // B*S*D
    float* kh    = qh + B * S * D;         // B*S*D
    float* vh    = kh + B * S * D;         // B*S*D
    float* ao    = vh + B * S * D;         // B*S*D (attn out, pre-Wo)

    // 1. recover pe table (2 MB of the 512 MB pos_emb)
    build_pe<<<(VOCAB * D + 255) / 256, 256, 0, stream>>>(pos_emb, pe);

    // 2. projections
    dim3 blk(256);
    dim3 gqkv(D / 64, (B * S) / 64);
    gemm_bt<<<gqkv, blk, 0, stream>>>(q, Wq, bq, nullptr, qh, B * S, D, D);
    gemm_bt<<<gqkv, blk, 0, stream>>>(k, Wk, bk, nullptr, kh, B * S, D, D);
    gemm_bt<<<gqkv, blk, 0, stream>>>(v, Wv, bv, nullptr, vh, B * S, D, D);
    dim3 gr(D / 64, (VOCAB + 63) / 64);
    gemm_bt<<<gr, blk, 0, stream>>>(pe, Wr, br, nullptr, rproj, VOCAB, D, D);

    // 3. fused relative attention
    attn_kernel<<<dim3(B * H, S / 16), blk, 0, stream>>>(qh, kh, vh, rproj,
                                                         u_bias, v_bias, ao);

    // 4. output projection + residual (into d_out), then in-place LN
    gemm_bt<<<gqkv, blk, 0, stream>>>(ao, Wo, bo, q, out, B * S, D, D);
    ln_kernel<<<B * S / 4, blk, 0, stream>>>(out, ln_g, ln_b);
}

// Round 2
// 142.289 us; speedup vs baseline: 7.3607x; 7.3607x over previous
//
#include <hip/hip_runtime.h>
#include <math.h>

#define B 8
#define S 512
#define D 512
#define H 8
#define DH 64
#define VOCAB (2 * (S - 1) + 1)   // 1023
#define GK 512

typedef unsigned short u16;
typedef __attribute__((ext_vector_type(8))) short s16x8;
typedef __attribute__((ext_vector_type(4))) float f32x4;

__device__ __forceinline__ u16 f2bf(float f) {
    union { float f; unsigned u; } a; a.f = f;
    unsigned r = a.u + 0x7FFF + ((a.u >> 16) & 1);
    return (u16)(r >> 16);
}
__device__ __forceinline__ float bf2f(u16 h) {
    union { unsigned u; float f; } a; a.u = ((unsigned)h) << 16;
    return a.f;
}

// ---------------------------------------------------------------------------
// Recover the 1023-row sinusoidal table from pos_emb (bf16 out).
// pos_emb[q,k,:] = pe[k - q + 511].
// ---------------------------------------------------------------------------
__global__ void build_pe(const float* __restrict__ pos_emb, u16* __restrict__ pe) {
    int idx = blockIdx.x * blockDim.x + threadIdx.x;
    if (idx >= VOCAB * D) return;
    int d = idx / D, c = idx % D;
    int q = (d < S) ? (S - 1) : 0;
    int k = (d < S) ? d : (d - (S - 1));
    pe[idx] = f2bf(pos_emb[(q * S + k) * D + c]);
}

// f32 -> bf16 cast, 8 elems/thread
__global__ void cast_bf16(const float* __restrict__ src, u16* __restrict__ dst, int n8) {
    int i = blockIdx.x * blockDim.x + threadIdx.x;
    if (i >= n8) return;
    float4 a = ((const float4*)src)[2 * i];
    float4 b = ((const float4*)src)[2 * i + 1];
    s16x8 o;
    o[0] = f2bf(a.x); o[1] = f2bf(a.y); o[2] = f2bf(a.z); o[3] = f2bf(a.w);
    o[4] = f2bf(b.x); o[5] = f2bf(b.y); o[6] = f2bf(b.z); o[7] = f2bf(b.w);
    ((s16x8*)dst)[i] = o;
}

// ---------------------------------------------------------------------------
// bf16 MFMA GEMM: C[M,512] = A[M,512] @ W[512,512]^T + bias
// 64x64 tile, BK=64, 4 waves each owning a 32x32 quadrant.
// Cf != nullptr: f32 output + residual.  Else bf16 output to Cb.
// ---------------------------------------------------------------------------
__global__ __launch_bounds__(256) void gemm_mfma(
    const u16* __restrict__ A, const u16* __restrict__ W,
    const float* __restrict__ bias, const float* __restrict__ resid,
    u16* __restrict__ Cb, float* __restrict__ Cf, int M)
{
    __shared__ u16 As[64][72];
    __shared__ u16 Ws[64][72];
    int tid = threadIdx.x;
    int m0 = blockIdx.y * 64, n0 = blockIdx.x * 64;
    int w = tid >> 6, lane = tid & 63;
    int wr = w >> 1, wc = w & 1;
    int lr = lane & 15, lk = lane >> 4;
    f32x4 acc[2][2] = {};
    s16x8 zero = (s16x8)(short)0;

    for (int k0 = 0; k0 < GK; k0 += 64) {
        #pragma unroll
        for (int i = 0; i < 2; ++i) {
            int g = tid + 256 * i;
            int r = g >> 3, c8 = (g & 7) * 8;
            int gm = m0 + r;
            s16x8 av = (gm < M) ? *(const s16x8*)&A[gm * GK + k0 + c8] : zero;
            *(s16x8*)&As[r][c8] = av;
            *(s16x8*)&Ws[r][c8] = *(const s16x8*)&W[(n0 + r) * GK + k0 + c8];
        }
        __syncthreads();
        #pragma unroll
        for (int ks = 0; ks < 2; ++ks) {
            s16x8 fa[2], fb[2];
            #pragma unroll
            for (int f = 0; f < 2; ++f) {
                fa[f] = *(const s16x8*)&As[wr * 32 + f * 16 + lr][ks * 32 + lk * 8];
                fb[f] = *(const s16x8*)&Ws[wc * 32 + f * 16 + lr][ks * 32 + lk * 8];
            }
            #pragma unroll
            for (int fm = 0; fm < 2; ++fm)
                #pragma unroll
                for (int fn = 0; fn < 2; ++fn)
                    acc[fm][fn] = __builtin_amdgcn_mfma_f32_16x16x32_bf16(
                        fa[fm], fb[fn], acc[fm][fn], 0, 0, 0);
        }
        __syncthreads();
    }
    #pragma unroll
    for (int fm = 0; fm < 2; ++fm) {
        #pragma unroll
        for (int r = 0; r < 4; ++r) {
            int m = m0 + wr * 32 + fm * 16 + lk * 4 + r;
            if (m >= M) continue;
            #pragma unroll
            for (int fn = 0; fn < 2; ++fn) {
                int n = n0 + wc * 32 + fn * 16 + lr;
                float v = acc[fm][fn][r] + bias[n];
                if (Cf) Cf[m * 512 + n] = v + resid[m * 512 + n];
                else    Cb[m * 512 + n] = f2bf(v);
            }
        }
    }
}

// ---------------------------------------------------------------------------
// Fused relative attention, MFMA + online softmax.
// Block = (b,h) x 64 q-rows; 4 waves, wave w owns rows [16w,16w+16).
// score[q,k] = ( Qu[q]*K[k] + Qv[q]*rproj[k-q+511] ) / 8
// bd computed as per-wave 16x80 band T then shift-gathered via LDS.
// ---------------------------------------------------------------------------
__global__ __launch_bounds__(256) void attn_mfma(
    const u16* __restrict__ qh, const u16* __restrict__ kh,
    const u16* __restrict__ vh, const u16* __restrict__ rproj,
    const float* __restrict__ u_bias, const float* __restrict__ v_bias,
    u16* __restrict__ ao)
{
    __shared__ u16 K_s[64][72];
    __shared__ u16 Vt_s[64][72];
    __shared__ u16 R_s[128][72];
    __shared__ float T_s[4][16][84];
    __shared__ u16 P_s[4][16][72];

    int bh = blockIdx.x;
    int b = bh >> 3, h = bh & 7;
    int q0 = blockIdx.y * 64;
    int tid = threadIdx.x, w = tid >> 6, lane = tid & 63;
    int lr = lane & 15, lk = lane >> 4;
    int woff = 48 - 16 * w;

    // Qu/Qv A-fragments in registers (wave-private, loaded once)
    s16x8 qu[2], qv[2];
    {
        int qrow = q0 + 16 * w + lr;
        const u16* qp = &qh[((b * S + qrow) * H + h) * DH];
        #pragma unroll
        for (int f = 0; f < 2; ++f) {
            int d0 = lk * 8 + f * 32;
            s16x8 qraw = *(const s16x8*)&qp[d0];
            s16x8 xu, xv;
            #pragma unroll
            for (int j = 0; j < 8; ++j) {
                float qf = bf2f((u16)qraw[j]);
                xu[j] = (short)f2bf(qf + u_bias[h * DH + d0 + j]);
                xv[j] = (short)f2bf(qf + v_bias[h * DH + d0 + j]);
            }
            qu[f] = xu; qv[f] = xv;
        }
    }

    float m_run[4], l_run[4];
    f32x4 opv[4] = {};
    #pragma unroll
    for (int r = 0; r < 4; ++r) { m_run[r] = -1e30f; l_run[r] = 0.f; }

    for (int kt = 0; kt < 8; ++kt) {
        int k0 = kt * 64;
        int rbase = k0 - q0 + 448;

        // ---- stage K (row-major), V (transposed), R band ----
        #pragma unroll
        for (int i = 0; i < 2; ++i) {
            int g = tid + 256 * i;
            int r = g >> 3, c8 = (g & 7) * 8;
            *(s16x8*)&K_s[r][c8] =
                *(const s16x8*)&kh[((b * S + k0 + r) * H + h) * DH + c8];
        }
        {
            int key = tid & 63, db = tid >> 6;
            const u16* vp = &vh[((b * S + k0 + key) * H + h) * DH + db * 16];
            s16x8 v0 = *(const s16x8*)&vp[0];
            s16x8 v1 = *(const s16x8*)&vp[8];
            #pragma unroll
            for (int e = 0; e < 8; ++e) {
                Vt_s[db * 16 + e][key]     = (u16)v0[e];
                Vt_s[db * 16 + 8 + e][key] = (u16)v1[e];
            }
        }
        #pragma unroll
        for (int i = 0; i < 4; ++i) {
            int g = tid + 256 * i;
            int j = g >> 3, c8 = (g & 7) * 8;
            int rr = rbase + j; if (rr > 1022) rr = 1022;
            *(s16x8*)&R_s[j][c8] =
                *(const s16x8*)&rproj[rr * D + h * DH + c8];
        }
        __syncthreads();

        // ---- ac = Qu @ K^T (16x64 per wave) ----
        f32x4 sacc[4] = {};
        #pragma unroll
        for (int ks = 0; ks < 2; ++ks) {
            s16x8 bfr[4];
            #pragma unroll
            for (int cf = 0; cf < 4; ++cf)
                bfr[cf] = *(const s16x8*)&K_s[cf * 16 + lr][ks * 32 + lk * 8];
            #pragma unroll
            for (int cf = 0; cf < 4; ++cf)
                sacc[cf] = __builtin_amdgcn_mfma_f32_16x16x32_bf16(
                    qu[ks], bfr[cf], sacc[cf], 0, 0, 0);
        }
        // ---- T = Qv @ Rband^T (16x80 per wave) ----
        f32x4 tacc[5] = {};
        #pragma unroll
        for (int ks = 0; ks < 2; ++ks) {
            #pragma unroll
            for (int cf = 0; cf < 5; ++cf) {
                s16x8 bfr = *(const s16x8*)&R_s[woff + cf * 16 + lr][ks * 32 + lk * 8];
                tacc[cf] = __builtin_amdgcn_mfma_f32_16x16x32_bf16(
                    qv[ks], bfr, tacc[cf], 0, 0, 0);
            }
        }
        #pragma unroll
        for (int cf = 0; cf < 5; ++cf)
            #pragma unroll
            for (int r = 0; r < 4; ++r)
                T_s[w][lk * 4 + r][cf * 16 + lr] = tacc[cf][r];
        asm volatile("s_waitcnt lgkmcnt(0)" ::: "memory");

        // ---- assemble scores with shift-gather, online softmax ----
        float sc_f[4][4];
        #pragma unroll
        for (int cf = 0; cf < 4; ++cf)
            #pragma unroll
            for (int r = 0; r < 4; ++r) {
                int ql = lk * 4 + r, kk = lr + cf * 16;
                sc_f[cf][r] = (sacc[cf][r] + T_s[w][ql][kk - ql + 15]) * 0.125f;
            }
        float mt[4];
        #pragma unroll
        for (int r = 0; r < 4; ++r)
            mt[r] = fmaxf(fmaxf(sc_f[0][r], sc_f[1][r]), fmaxf(sc_f[2][r], sc_f[3][r]));
        #pragma unroll
        for (int mask = 1; mask < 16; mask <<= 1)
            #pragma unroll
            for (int r = 0; r < 4; ++r)
                mt[r] = fmaxf(mt[r], __shfl_xor(mt[r], mask, 64));
        float al[4], psum[4];
        #pragma unroll
        for (int r = 0; r < 4; ++r) {
            float mn = fmaxf(m_run[r], mt[r]);
            al[r] = __expf(m_run[r] - mn);
            m_run[r] = mn;
            psum[r] = 0.f;
        }
        #pragma unroll
        for (int cf = 0; cf < 4; ++cf)
            #pragma unroll
            for (int r = 0; r < 4; ++r) {
                float p = __expf(sc_f[cf][r] - m_run[r]);
                psum[r] += p;
                P_s[w][lk * 4 + r][lr + cf * 16] = f2bf(p);
            }
        #pragma unroll
        for (int mask = 1; mask < 16; mask <<= 1)
            #pragma unroll
            for (int r = 0; r < 4; ++r)
                psum[r] += __shfl_xor(psum[r], mask, 64);
        #pragma unroll
        for (int r = 0; r < 4; ++r)
            l_run[r] = l_run[r] * al[r] + psum[r];
        #pragma unroll
        for (int cf = 0; cf < 4; ++cf)
            #pragma unroll
            for (int r = 0; r < 4; ++r)
                opv[cf][r] *= al[r];
        asm volatile("s_waitcnt lgkmcnt(0)" ::: "memory");

        // ---- PV: opv += P @ V ----
        #pragma unroll
        for (int ks = 0; ks < 2; ++ks) {
            s16x8 pa = *(const s16x8*)&P_s[w][lr][ks * 32 + lk * 8];
            #pragma unroll
            for (int cf = 0; cf < 4; ++cf) {
                s16x8 vf = *(const s16x8*)&Vt_s[cf * 16 + lr][ks * 32 + lk * 8];
                opv[cf] = __builtin_amdgcn_mfma_f32_16x16x32_bf16(
                    pa, vf, opv[cf], 0, 0, 0);
            }
        }
        __syncthreads();
    }

    // ---- write attention output (bf16) ----
    #pragma unroll
    for (int cf = 0; cf < 4; ++cf)
        #pragma unroll
        for (int r = 0; r < 4; ++r) {
            int qrow = q0 + 16 * w + lk * 4 + r;
            ao[((b * S + qrow) * H + h) * DH + lr + 16 * cf] =
                f2bf(opv[cf][r] / l_run[r]);
        }
}

// ---------------------------------------------------------------------------
// In-place LayerNorm over last dim (D=512). One wave per row.
// ---------------------------------------------------------------------------
__global__ __launch_bounds__(256) void ln_kernel(
    float* __restrict__ out, const float* __restrict__ g, const float* __restrict__ bta)
{
    int row = blockIdx.x * 4 + threadIdx.x / 64;
    int lane = threadIdx.x % 64;
    float vals[8];
    float sum = 0.f;
    #pragma unroll
    for (int j = 0; j < 8; ++j) {
        vals[j] = out[row * D + lane + j * 64];
        sum += vals[j];
    }
    #pragma unroll
    for (int off = 32; off; off >>= 1) sum += __shfl_xor(sum, off, 64);
    float mu = sum / (float)D;
    float sq = 0.f;
    #pragma unroll
    for (int j = 0; j < 8; ++j) { float dv = vals[j] - mu; sq += dv * dv; }
    #pragma unroll
    for (int off = 32; off; off >>= 1) sq += __shfl_xor(sq, off, 64);
    float rstd = rsqrtf(sq / (float)D + 1e-5f);
    #pragma unroll
    for (int j = 0; j < 8; ++j) {
        int c = lane + j * 64;
        out[row * D + c] = (vals[j] - mu) * rstd * g[c] + bta[c];
    }
}

// ---------------------------------------------------------------------------
extern "C" void kernel_launch(void* const* d_in, const int* in_sizes, int n_in,
                              void* d_out, int out_size, void* d_ws, size_t ws_size,
                              hipStream_t stream) {
    const float* q       = (const float*)d_in[0];
    const float* k       = (const float*)d_in[1];
    const float* v       = (const float*)d_in[2];
    const float* pos_emb = (const float*)d_in[3];
    const float* Wq = (const float*)d_in[4];  const float* bq = (const float*)d_in[5];
    const float* Wk = (const float*)d_in[6];  const float* bk = (const float*)d_in[7];
    const float* Wv = (const float*)d_in[8];  const float* bv = (const float*)d_in[9];
    const float* Wr = (const float*)d_in[10]; const float* br = (const float*)d_in[11];
    const float* Wo = (const float*)d_in[12]; const float* bo = (const float*)d_in[13];
    const float* u_bias = (const float*)d_in[14];
    const float* v_bias = (const float*)d_in[15];
    const float* ln_g = (const float*)d_in[16];
    const float* ln_b = (const float*)d_in[17];

    float* out = (float*)d_out;
    u16* ws = (u16*)d_ws;

    const int NBS = B * S * D;        // 2097152
    const int NW  = D * D;            // 262144
    const int NPE = VOCAB * D;        // 523776

    u16* pe_b  = ws;                  // NPE
    u16* qb    = pe_b + NPE;          // NBS
    u16* kb    = qb + NBS;
    u16* vb    = kb + NBS;
    u16* Wqb   = vb + NBS;            // NW x5
    u16* Wkb   = Wqb + NW;
    u16* Wvb   = Wkb + NW;
    u16* Wrb   = Wvb + NW;
    u16* Wob   = Wrb + NW;
    u16* rproj = Wob + NW;            // NPE
    u16* qhb   = rproj + NPE;         // NBS
    u16* khb   = qhb + NBS;
    u16* vhb   = khb + NBS;
    u16* aob   = vhb + NBS;           // NBS

    dim3 blk(256);

    // 1. pe table (bf16) + input/weight casts
    build_pe<<<(NPE + 255) / 256, blk, 0, stream>>>(pos_emb, pe_b);
    cast_bf16<<<NBS / 8 / 256, blk, 0, stream>>>(q, qb, NBS / 8);
    cast_bf16<<<NBS / 8 / 256, blk, 0, stream>>>(k, kb, NBS / 8);
    cast_bf16<<<NBS / 8 / 256, blk, 0, stream>>>(v, vb, NBS / 8);
    cast_bf16<<<NW / 8 / 256, blk, 0, stream>>>(Wq, Wqb, NW / 8);
    cast_bf16<<<NW / 8 / 256, blk, 0, stream>>>(Wk, Wkb, NW / 8);
    cast_bf16<<<NW / 8 / 256, blk, 0, stream>>>(Wv, Wvb, NW / 8);
    cast_bf16<<<NW / 8 / 256, blk, 0, stream>>>(Wr, Wrb, NW / 8);
    cast_bf16<<<NW / 8 / 256, blk, 0, stream>>>(Wo, Wob, NW / 8);

    // 2. projections (bf16 MFMA GEMM)
    dim3 gp(8, 64);
    gemm_mfma<<<gp, blk, 0, stream>>>(qb, Wqb, bq, nullptr, qhb, nullptr, B * S);
    gemm_mfma<<<gp, blk, 0, stream>>>(kb, Wkb, bk, nullptr, khb, nullptr, B * S);
    gemm_mfma<<<gp, blk, 0, stream>>>(vb, Wvb, bv, nullptr, vhb, nullptr, B * S);
    gemm_mfma<<<dim3(8, 16), blk, 0, stream>>>(pe_b, Wrb, br, nullptr, rproj, nullptr, VOCAB);

    // 3. fused relative attention
    attn_mfma<<<dim3(B * H, S / 64), blk, 0, stream>>>(qhb, khb, vhb, rproj,
                                                       u_bias, v_bias, aob);

    // 4. output projection + residual (f32) + LayerNorm
    gemm_mfma<<<gp, blk, 0, stream>>>(aob, Wob, bo, q, nullptr, out, B * S);
    ln_kernel<<<B * S / 4, blk, 0, stream>>>(out, ln_g, ln_b);
}

// Round 6
// 91.123 us; speedup vs baseline: 11.4938x; 1.5615x over previous
//
#include <hip/hip_runtime.h>
#include <math.h>

#define B 8
#define S 512
#define D 512
#define H 8
#define DH 64
#define VOCAB (2 * (S - 1) + 1)   // 1023
#define GK 512
// NOTE: B*S = 4096. Rounds 3-5 failed because proj grids covered only 2048
// rows (identical absmax 4.65625 from deterministic 0xAA poison downstream).

typedef unsigned short u16;
typedef __attribute__((ext_vector_type(8))) short s16x8;
typedef __attribute__((ext_vector_type(4))) float f32x4;

__device__ __forceinline__ u16 f2bf(float f) {
    union { float f; unsigned u; } a; a.f = f;
    unsigned r = a.u + 0x7FFF + ((a.u >> 16) & 1);
    return (u16)(r >> 16);
}
__device__ __forceinline__ float bf2f(u16 h) {
    union { unsigned u; float f; } a; a.u = ((unsigned)h) << 16;
    return a.f;
}
__device__ __forceinline__ void cvt8(const float* __restrict__ s, u16* __restrict__ d) {
    float4 a = *(const float4*)s;
    float4 b = *(const float4*)(s + 4);
    s16x8 o;
    o[0] = f2bf(a.x); o[1] = f2bf(a.y); o[2] = f2bf(a.z); o[3] = f2bf(a.w);
    o[4] = f2bf(b.x); o[5] = f2bf(b.y); o[6] = f2bf(b.z); o[7] = f2bf(b.w);
    *(s16x8*)d = o;
}

#define GLOAD16(gp, lp) __builtin_amdgcn_global_load_lds( \
    (const __attribute__((address_space(1))) unsigned int*)(gp), \
    (__attribute__((address_space(3))) unsigned int*)(lp), 16, 0, 0)

// ---------------------------------------------------------------------------
// Fused prep: pe-table recovery (bf16, 1024 rows w/ zero pad row) +
// 5 weight casts + q/k/v casts. Grid-strided, 8 elems/thread/iter.
// ---------------------------------------------------------------------------
__global__ __launch_bounds__(256) void prep(
    const float* __restrict__ pos_emb,
    const float* __restrict__ q, const float* __restrict__ k, const float* __restrict__ v,
    const float* __restrict__ Wq, const float* __restrict__ Wk, const float* __restrict__ Wv,
    const float* __restrict__ Wr, const float* __restrict__ Wo,
    u16* __restrict__ pe_b, u16* __restrict__ qb, u16* __restrict__ kb, u16* __restrict__ vb,
    u16* __restrict__ Wqb, u16* __restrict__ Wkb, u16* __restrict__ Wvb,
    u16* __restrict__ Wrb, u16* __restrict__ Wob)
{
    const int NPE8 = (1024 * 512) / 8;   // 65536
    const int NW8  = (512 * 512) / 8;    // 32768
    const int NBS8 = (B * S * D) / 8;    // 262144
    const int total = NPE8 + 5 * NW8 + 3 * NBS8;
    for (int i = blockIdx.x * 256 + threadIdx.x; i < total; i += gridDim.x * 256) {
        if (i < NPE8) {
            int e = i * 8;
            int row = e >> 9, col = e & 511;
            if (row >= VOCAB) {
                *(s16x8*)&pe_b[e] = (s16x8)(short)0;
            } else {
                int qq = (row < S) ? (S - 1) : 0;
                int kk = (row < S) ? row : (row - (S - 1));
                cvt8(&pos_emb[(qq * S + kk) * D + col], &pe_b[e]);
            }
            continue;
        }
        int j = i - NPE8;
        if (j < 5 * NW8) {
            int wi = j >> 15;
            int e = (j & (NW8 - 1)) * 8;
            const float* src; u16* dst;
            if      (wi == 0) { src = Wq; dst = Wqb; }
            else if (wi == 1) { src = Wk; dst = Wkb; }
            else if (wi == 2) { src = Wv; dst = Wvb; }
            else if (wi == 3) { src = Wr; dst = Wrb; }
            else              { src = Wo; dst = Wob; }
            cvt8(&src[e], &dst[e]);
            continue;
        }
        int j2 = j - 5 * NW8;
        int qi = j2 >> 18;
        int e = (j2 & (NBS8 - 1)) * 8;
        const float* src; u16* dst;
        if      (qi == 0) { src = q; dst = qb; }
        else if (qi == 1) { src = k; dst = kb; }
        else              { src = v; dst = vb; }
        cvt8(&src[e], &dst[e]);
    }
}

// ---------------------------------------------------------------------------
// 128x128-tile bf16 MFMA GEMM (m97 structure): BK=64, 4 waves each owning a
// 64x64 quadrant (4x4 16x16x32 fragments), global_load_lds staging with
// wave-uniform LDS base (HW adds lane*16B), linear [128][64] LDS layout.
// C[M,512] = A[M,512] @ W[512,512]^T + bias  (+resid, f32 out if F32OUT)
// ---------------------------------------------------------------------------
template<bool F32OUT>
__device__ __forceinline__ void gemm128_body(
    const u16* __restrict__ A, const u16* __restrict__ W,
    const float* __restrict__ bias, const float* __restrict__ resid,
    u16* __restrict__ Cb, float* __restrict__ Cf,
    int m0, int n0, u16* As, u16* Ws)
{
    int tid = threadIdx.x;
    int w = tid >> 6, lane = tid & 63;
    int wr = w >> 1, wc = w & 1;
    int lr = lane & 15, lk = lane >> 4;
    f32x4 acc[4][4] = {};

    for (int k0 = 0; k0 < GK; k0 += 64) {
        #pragma unroll
        for (int l = 0; l < 4; ++l) {
            int chunk = w * 4 + l;
            int r = chunk * 8 + (lane >> 3);
            int c = (lane & 7) * 8;
            GLOAD16(&A[(m0 + r) * GK + k0 + c], &As[chunk * 512]);
            GLOAD16(&W[(n0 + r) * GK + k0 + c], &Ws[chunk * 512]);
        }
        __syncthreads();
        #pragma unroll
        for (int ks = 0; ks < 2; ++ks) {
            s16x8 fa[4], fb[4];
            #pragma unroll
            for (int f = 0; f < 4; ++f) {
                fa[f] = *(const s16x8*)&As[(wr * 64 + f * 16 + lr) * 64 + ks * 32 + lk * 8];
                fb[f] = *(const s16x8*)&Ws[(wc * 64 + f * 16 + lr) * 64 + ks * 32 + lk * 8];
            }
            #pragma unroll
            for (int fm = 0; fm < 4; ++fm)
                #pragma unroll
                for (int fn = 0; fn < 4; ++fn)
                    acc[fm][fn] = __builtin_amdgcn_mfma_f32_16x16x32_bf16(
                        fa[fm], fb[fn], acc[fm][fn], 0, 0, 0);
        }
        __syncthreads();
    }
    #pragma unroll
    for (int fm = 0; fm < 4; ++fm) {
        #pragma unroll
        for (int r = 0; r < 4; ++r) {
            int m = m0 + wr * 64 + fm * 16 + lk * 4 + r;
            #pragma unroll
            for (int fn = 0; fn < 4; ++fn) {
                int n = n0 + wc * 64 + fn * 16 + lr;
                float vv = acc[fm][fn][r] + bias[n];
                if (F32OUT) Cf[m * 512 + n] = vv + resid[m * 512 + n];
                else        Cb[m * 512 + n] = f2bf(vv);
            }
        }
    }
}

// Batched QKV + R projections: z = 0..2 -> q/k/v (M=4096), z = 3 -> pe (M=1024).
__global__ __launch_bounds__(256) void proj_qkvr(
    const u16* __restrict__ qb, const u16* __restrict__ kb, const u16* __restrict__ vb,
    const u16* __restrict__ pe_b,
    const u16* __restrict__ Wqb, const u16* __restrict__ Wkb, const u16* __restrict__ Wvb,
    const u16* __restrict__ Wrb,
    const float* __restrict__ bq, const float* __restrict__ bk, const float* __restrict__ bv,
    const float* __restrict__ br,
    u16* __restrict__ qhb, u16* __restrict__ khb, u16* __restrict__ vhb,
    u16* __restrict__ rproj)
{
    __shared__ u16 As[128 * 64];
    __shared__ u16 Ws[128 * 64];
    const u16 *A, *W; const float* bias; u16* C;
    int z = blockIdx.z;
    if      (z == 0) { A = qb;   W = Wqb; bias = bq; C = qhb; }
    else if (z == 1) { A = kb;   W = Wkb; bias = bk; C = khb; }
    else if (z == 2) { A = vb;   W = Wvb; bias = bv; C = vhb; }
    else             { A = pe_b; W = Wrb; bias = br; C = rproj;
                       if (blockIdx.y >= 8) return; }   // pe: M=1024 -> 8 y-blocks
    gemm128_body<false>(A, W, bias, nullptr, C, nullptr,
                        blockIdx.y * 128, blockIdx.x * 128, As, Ws);
}

// Output projection + residual, f32 out.
__global__ __launch_bounds__(256) void proj_out(
    const u16* __restrict__ aob, const u16* __restrict__ Wob,
    const float* __restrict__ bo, const float* __restrict__ resid,
    float* __restrict__ out)
{
    __shared__ u16 As[128 * 64];
    __shared__ u16 Ws[128 * 64];
    gemm128_body<true>(aob, Wob, bo, resid, nullptr, out,
                       blockIdx.y * 128, blockIdx.x * 128, As, Ws);
}

// ---------------------------------------------------------------------------
// Fused relative attention, MFMA + online softmax (verified round 2).
// ---------------------------------------------------------------------------
__global__ __launch_bounds__(256) void attn_mfma(
    const u16* __restrict__ qh, const u16* __restrict__ kh,
    const u16* __restrict__ vh, const u16* __restrict__ rproj,
    const float* __restrict__ u_bias, const float* __restrict__ v_bias,
    u16* __restrict__ ao)
{
    __shared__ u16 K_s[64][72];
    __shared__ u16 Vt_s[64][72];
    __shared__ u16 R_s[128][72];
    __shared__ float T_s[4][16][84];
    __shared__ u16 P_s[4][16][72];

    int bh = blockIdx.x;
    int b = bh >> 3, h = bh & 7;
    int q0 = blockIdx.y * 64;
    int tid = threadIdx.x, w = tid >> 6, lane = tid & 63;
    int lr = lane & 15, lk = lane >> 4;
    int woff = 48 - 16 * w;

    s16x8 qu[2], qv[2];
    {
        int qrow = q0 + 16 * w + lr;
        const u16* qp = &qh[((b * S + qrow) * H + h) * DH];
        #pragma unroll
        for (int f = 0; f < 2; ++f) {
            int d0 = lk * 8 + f * 32;
            s16x8 qraw = *(const s16x8*)&qp[d0];
            s16x8 xu, xv;
            #pragma unroll
            for (int j = 0; j < 8; ++j) {
                float qf = bf2f((u16)qraw[j]);
                xu[j] = (short)f2bf(qf + u_bias[h * DH + d0 + j]);
                xv[j] = (short)f2bf(qf + v_bias[h * DH + d0 + j]);
            }
            qu[f] = xu; qv[f] = xv;
        }
    }

    float m_run[4], l_run[4];
    f32x4 opv[4] = {};
    #pragma unroll
    for (int r = 0; r < 4; ++r) { m_run[r] = -1e30f; l_run[r] = 0.f; }

    for (int kt = 0; kt < 8; ++kt) {
        int k0 = kt * 64;
        int rbase = k0 - q0 + 448;

        #pragma unroll
        for (int i = 0; i < 2; ++i) {
            int g = tid + 256 * i;
            int r = g >> 3, c8 = (g & 7) * 8;
            *(s16x8*)&K_s[r][c8] =
                *(const s16x8*)&kh[((b * S + k0 + r) * H + h) * DH + c8];
        }
        {
            int key = tid & 63, db = tid >> 6;
            const u16* vp = &vh[((b * S + k0 + key) * H + h) * DH + db * 16];
            s16x8 v0 = *(const s16x8*)&vp[0];
            s16x8 v1 = *(const s16x8*)&vp[8];
            #pragma unroll
            for (int e = 0; e < 8; ++e) {
                Vt_s[db * 16 + e][key]     = (u16)v0[e];
                Vt_s[db * 16 + 8 + e][key] = (u16)v1[e];
            }
        }
        #pragma unroll
        for (int i = 0; i < 4; ++i) {
            int g = tid + 256 * i;
            int jr = g >> 3, c8 = (g & 7) * 8;
            int rr = rbase + jr; if (rr > 1022) rr = 1022;
            *(s16x8*)&R_s[jr][c8] =
                *(const s16x8*)&rproj[rr * D + h * DH + c8];
        }
        __syncthreads();

        f32x4 sacc[4] = {};
        #pragma unroll
        for (int ks = 0; ks < 2; ++ks) {
            s16x8 bfr[4];
            #pragma unroll
            for (int cf = 0; cf < 4; ++cf)
                bfr[cf] = *(const s16x8*)&K_s[cf * 16 + lr][ks * 32 + lk * 8];
            #pragma unroll
            for (int cf = 0; cf < 4; ++cf)
                sacc[cf] = __builtin_amdgcn_mfma_f32_16x16x32_bf16(
                    qu[ks], bfr[cf], sacc[cf], 0, 0, 0);
        }
        f32x4 tacc[5] = {};
        #pragma unroll
        for (int ks = 0; ks < 2; ++ks) {
            #pragma unroll
            for (int cf = 0; cf < 5; ++cf) {
                s16x8 bfr = *(const s16x8*)&R_s[woff + cf * 16 + lr][ks * 32 + lk * 8];
                tacc[cf] = __builtin_amdgcn_mfma_f32_16x16x32_bf16(
                    qv[ks], bfr, tacc[cf], 0, 0, 0);
            }
        }
        #pragma unroll
        for (int cf = 0; cf < 5; ++cf)
            #pragma unroll
            for (int r = 0; r < 4; ++r)
                T_s[w][lk * 4 + r][cf * 16 + lr] = tacc[cf][r];
        asm volatile("s_waitcnt lgkmcnt(0)" ::: "memory");

        float sc_f[4][4];
        #pragma unroll
        for (int cf = 0; cf < 4; ++cf)
            #pragma unroll
            for (int r = 0; r < 4; ++r) {
                int ql = lk * 4 + r, kk = lr + cf * 16;
                sc_f[cf][r] = (sacc[cf][r] + T_s[w][ql][kk - ql + 15]) * 0.125f;
            }
        float mt[4];
        #pragma unroll
        for (int r = 0; r < 4; ++r)
            mt[r] = fmaxf(fmaxf(sc_f[0][r], sc_f[1][r]), fmaxf(sc_f[2][r], sc_f[3][r]));
        #pragma unroll
        for (int mask = 1; mask < 16; mask <<= 1)
            #pragma unroll
            for (int r = 0; r < 4; ++r)
                mt[r] = fmaxf(mt[r], __shfl_xor(mt[r], mask, 64));
        float al[4], psum[4];
        #pragma unroll
        for (int r = 0; r < 4; ++r) {
            float mn = fmaxf(m_run[r], mt[r]);
            al[r] = __expf(m_run[r] - mn);
            m_run[r] = mn;
            psum[r] = 0.f;
        }
        #pragma unroll
        for (int cf = 0; cf < 4; ++cf)
            #pragma unroll
            for (int r = 0; r < 4; ++r) {
                float p = __expf(sc_f[cf][r] - m_run[r]);
                psum[r] += p;
                P_s[w][lk * 4 + r][lr + cf * 16] = f2bf(p);
            }
        #pragma unroll
        for (int mask = 1; mask < 16; mask <<= 1)
            #pragma unroll
            for (int r = 0; r < 4; ++r)
                psum[r] += __shfl_xor(psum[r], mask, 64);
        #pragma unroll
        for (int r = 0; r < 4; ++r)
            l_run[r] = l_run[r] * al[r] + psum[r];
        #pragma unroll
        for (int cf = 0; cf < 4; ++cf)
            #pragma unroll
            for (int r = 0; r < 4; ++r)
                opv[cf][r] *= al[r];
        asm volatile("s_waitcnt lgkmcnt(0)" ::: "memory");

        #pragma unroll
        for (int ks = 0; ks < 2; ++ks) {
            s16x8 pa = *(const s16x8*)&P_s[w][lr][ks * 32 + lk * 8];
            #pragma unroll
            for (int cf = 0; cf < 4; ++cf) {
                s16x8 vf = *(const s16x8*)&Vt_s[cf * 16 + lr][ks * 32 + lk * 8];
                opv[cf] = __builtin_amdgcn_mfma_f32_16x16x32_bf16(
                    pa, vf, opv[cf], 0, 0, 0);
            }
        }
        __syncthreads();
    }

    #pragma unroll
    for (int cf = 0; cf < 4; ++cf)
        #pragma unroll
        for (int r = 0; r < 4; ++r) {
            int qrow = q0 + 16 * w + lk * 4 + r;
            ao[((b * S + qrow) * H + h) * DH + lr + 16 * cf] =
                f2bf(opv[cf][r] / l_run[r]);
        }
}

// ---------------------------------------------------------------------------
// In-place LayerNorm over last dim (D=512). One wave per row.
// ---------------------------------------------------------------------------
__global__ __launch_bounds__(256) void ln_kernel(
    float* __restrict__ out, const float* __restrict__ g, const float* __restrict__ bta)
{
    int row = blockIdx.x * 4 + threadIdx.x / 64;
    int lane = threadIdx.x % 64;
    float vals[8];
    float sum = 0.f;
    #pragma unroll
    for (int j = 0; j < 8; ++j) {
        vals[j] = out[row * D + lane + j * 64];
        sum += vals[j];
    }
    #pragma unroll
    for (int off = 32; off; off >>= 1) sum += __shfl_xor(sum, off, 64);
    float mu = sum / (float)D;
    float sq = 0.f;
    #pragma unroll
    for (int j = 0; j < 8; ++j) { float dv = vals[j] - mu; sq += dv * dv; }
    #pragma unroll
    for (int off = 32; off; off >>= 1) sq += __shfl_xor(sq, off, 64);
    float rstd = rsqrtf(sq / (float)D + 1e-5f);
    #pragma unroll
    for (int j = 0; j < 8; ++j) {
        int c = lane + j * 64;
        out[row * D + c] = (vals[j] - mu) * rstd * g[c] + bta[c];
    }
}

// ---------------------------------------------------------------------------
extern "C" void kernel_launch(void* const* d_in, const int* in_sizes, int n_in,
                              void* d_out, int out_size, void* d_ws, size_t ws_size,
                              hipStream_t stream) {
    const float* q       = (const float*)d_in[0];
    const float* k       = (const float*)d_in[1];
    const float* v       = (const float*)d_in[2];
    const float* pos_emb = (const float*)d_in[3];
    const float* Wq = (const float*)d_in[4];  const float* bq = (const float*)d_in[5];
    const float* Wk = (const float*)d_in[6];  const float* bk = (const float*)d_in[7];
    const float* Wv = (const float*)d_in[8];  const float* bv = (const float*)d_in[9];
    const float* Wr = (const float*)d_in[10]; const float* br = (const float*)d_in[11];
    const float* Wo = (const float*)d_in[12]; const float* bo = (const float*)d_in[13];
    const float* u_bias = (const float*)d_in[14];
    const float* v_bias = (const float*)d_in[15];
    const float* ln_g = (const float*)d_in[16];
    const float* ln_b = (const float*)d_in[17];

    float* out = (float*)d_out;
    u16* ws = (u16*)d_ws;

    const int NBS = B * S * D;        // 2097152 (B*S = 4096 rows!)
    const int NW  = D * D;            // 262144
    const int NPE = 1024 * 512;       // padded pe/rproj (row 1023 zero)

    u16* pe_b  = ws;
    u16* qb    = pe_b + NPE;
    u16* kb    = qb + NBS;
    u16* vb    = kb + NBS;
    u16* Wqb   = vb + NBS;
    u16* Wkb   = Wqb + NW;
    u16* Wvb   = Wkb + NW;
    u16* Wrb   = Wvb + NW;
    u16* Wob   = Wrb + NW;
    u16* rproj = Wob + NW;
    u16* qhb   = rproj + NPE;
    u16* khb   = qhb + NBS;
    u16* vhb   = khb + NBS;
    u16* aob   = vhb + NBS;

    dim3 blk(256);

    prep<<<2048, blk, 0, stream>>>(pos_emb, q, k, v, Wq, Wk, Wv, Wr, Wo,
                                   pe_b, qb, kb, vb, Wqb, Wkb, Wvb, Wrb, Wob);

    // GRID FIX: y=32 covers all 4096 rows (was 16 -> half the rows poisoned).
    proj_qkvr<<<dim3(4, 32, 4), blk, 0, stream>>>(
        qb, kb, vb, pe_b, Wqb, Wkb, Wvb, Wrb, bq, bk, bv, br,
        qhb, khb, vhb, rproj);

    attn_mfma<<<dim3(B * H, S / 64), blk, 0, stream>>>(qhb, khb, vhb, rproj,
                                                       u_bias, v_bias, aob);

    proj_out<<<dim3(4, 32), blk, 0, stream>>>(aob, Wob, bo, q, out);

    ln_kernel<<<B * S / 4, blk, 0, stream>>>(out, ln_g, ln_b);
}